// Round 10
// baseline (44.076 us; speedup 1.0000x reference)
//
#include <hip/hip_runtime.h>

#define BS  16
#define NN  256
#define HID 128

typedef __attribute__((ext_vector_type(8))) float float8;

// 512 blocks: XCD x gets swz in [64x, 64x+64) = batches 2x, 2x+1.
__device__ __forceinline__ int xcd_swz(int bid) {
    return (bid & 7) * 64 + (bid >> 3);
}

// ---------------------------------------------------------------------------
// K1: 512 blocks, 512 threads, 8 rows/block. Split-K quarters; weights read
// once per block; deep load pipelining (unroll 4 = 16 loads in flight).
// ---------------------------------------------------------------------------
__global__ __launch_bounds__(512, 4) void gat_k1(
    const float* __restrict__ x, const float* __restrict__ W_fc,
    const float* __restrict__ b_fc, const float* __restrict__ W_a1,
    const float* __restrict__ b_a1, const float* __restrict__ W_out,
    float* __restrict__ aiT, float* __restrict__ ajT, float* __restrict__ g)
{
    __shared__ __align__(16) float xs[8][HID];           // 4KB
    __shared__ __align__(16) float hs[8][HID];           // 4KB
    __shared__ __align__(16) float red[4][8][HID];       // 16KB

    const int tid = threadIdx.x;
    const int k   = tid & 127;
    const int q   = tid >> 7;                 // 0..3
    const int swz = xcd_swz(blockIdx.x);
    const int r0  = swz * 8;                  // flat row = b*NN + n0
    const int b   = r0 >> 8;
    const int n0  = r0 & 255;

    for (int t = tid; t < 8 * HID; t += 512)
        xs[t >> 7][t & 127] = x[r0 * HID + t];
    __syncthreads();

    // ---- phase 1: h partials, split-K quarter d in [32q, 32q+32) ----
    {
        float acc[8] = {0,0,0,0,0,0,0,0};
        const int dq = 32 * q;
        #pragma unroll 4
        for (int d = 0; d < 32; d += 4) {
            float w[4];
            #pragma unroll
            for (int t = 0; t < 4; ++t) w[t] = W_fc[(dq + d + t) * HID + k];
            #pragma unroll
            for (int r = 0; r < 8; ++r) {
                const float4 xv = *(const float4*)&xs[r][dq + d];
                acc[r] += xv.x * w[0] + xv.y * w[1] + xv.z * w[2] + xv.w * w[3];
            }
        }
        #pragma unroll
        for (int r = 0; r < 8; ++r) red[q][r][k] = acc[r];
    }
    __syncthreads();

    // ---- reduce h ----
    {
        const float bf = b_fc[k];
        #pragma unroll
        for (int r2 = 0; r2 < 2; ++r2) {
            const int r = 2 * q + r2;
            hs[r][k] = (red[0][r][k] + red[1][r][k])
                     + (red[2][r][k] + red[3][r][k]) + bf;
        }
    }
    __syncthreads();

    // ---- phase 2a: q0/q1 -> ai d-halves; q2/q3 -> aj d-halves ----
    {
        const int is_aj = q >> 1;
        const int half  = q & 1;
        const float* Wp = W_a1 + (is_aj * HID + half * 64) * HID;
        float acc[8] = {0,0,0,0,0,0,0,0};
        const int hb = half * 64;
        #pragma unroll 4
        for (int d = 0; d < 64; d += 4) {
            float w[4];
            #pragma unroll
            for (int t = 0; t < 4; ++t) w[t] = Wp[(d + t) * HID + k];
            #pragma unroll
            for (int r = 0; r < 8; ++r) {
                const float4 hv = *(const float4*)&hs[r][hb + d];
                acc[r] += hv.x * w[0] + hv.y * w[1] + hv.z * w[2] + hv.w * w[3];
            }
        }
        #pragma unroll
        for (int r = 0; r < 8; ++r) red[q][r][k] = acc[r];
    }
    __syncthreads();

    // ---- reduce + transposed store ----
    {
        const int is_aj = q >> 1;
        const int rb4   = (q & 1) * 4;
        const float bias = is_aj ? 0.f : b_a1[k];
        const int p0 = 2 * is_aj, p1 = 2 * is_aj + 1;
        float4 v;
        v.x = red[p0][rb4 + 0][k] + red[p1][rb4 + 0][k] + bias;
        v.y = red[p0][rb4 + 1][k] + red[p1][rb4 + 1][k] + bias;
        v.z = red[p0][rb4 + 2][k] + red[p1][rb4 + 2][k] + bias;
        v.w = red[p0][rb4 + 3][k] + red[p1][rb4 + 3][k] + bias;
        float* dst = (is_aj ? ajT : aiT) + (b * HID + k) * NN + n0 + rb4;
        *(float4*)dst = v;
    }
    __syncthreads();

    // ---- phase 2b: g partials ----
    {
        float acc[8] = {0,0,0,0,0,0,0,0};
        const int dq = 32 * q;
        #pragma unroll 4
        for (int d = 0; d < 32; d += 4) {
            float w[4];
            #pragma unroll
            for (int t = 0; t < 4; ++t) w[t] = W_out[(dq + d + t) * HID + k];
            #pragma unroll
            for (int r = 0; r < 8; ++r) {
                const float4 hv = *(const float4*)&hs[r][dq + d];
                acc[r] += hv.x * w[0] + hv.y * w[1] + hv.z * w[2] + hv.w * w[3];
            }
        }
        #pragma unroll
        for (int r = 0; r < 8; ++r) red[q][r][k] = acc[r];
    }
    __syncthreads();

    {
        #pragma unroll
        for (int r2 = 0; r2 < 2; ++r2) {
            const int r = 2 * q + r2;
            g[(r0 + r) * HID + k] = (red[0][r][k] + red[1][r][k])
                                  + (red[2][r][k] + red[3][r][k]);
        }
    }
}

// ---------------------------------------------------------------------------
// K2: 512 blocks, 512 threads, 8-row i-tile. Phase A: wave = (k-half,
// j-quarter) x all 8 rows; aj via 2x16-register load pipeline (32 loads in
// flight, covers L3 latency); ai via wave-uniform float8 scalar loads (zero
// LDS in the hot loop). e-halves reduced in LDS. Softmax 1 row/wave.
// Phase B: 4-way j-split, deep unroll, LDS reduce. out = attn@g + b_out.
// ---------------------------------------------------------------------------
__global__ __launch_bounds__(512, 4) void gat_k2(
    const float* __restrict__ aiT, const float* __restrict__ ajT,
    const float* __restrict__ g,  const int* __restrict__ adj,
    const float* __restrict__ w_a2, const float* __restrict__ b_a2,
    const float* __restrict__ b_out, float* __restrict__ out)
{
    __shared__ __align__(16) float buf[2 * 8 * NN];   // 16KB: e-halves, then red
    __shared__ __align__(16) float ep[8 * NN];        // 8KB: p

    const int tid = threadIdx.x;
    const int swz = xcd_swz(blockIdx.x);
    const int b   = swz >> 5;
    const int i0  = (swz & 31) * 8;
    const int wv  = tid >> 6, lane = tid & 63;

    // adj prefetch in softmax layout (row wv, cols 4*lane..+3); overlaps phase A
    const int4 am = *(const int4*)(adj + (b * NN + i0 + wv) * NN + 4 * lane);

    // ---- phase A: partial e, k-half kh, j-quarter jq, all 8 rows ----
    const int kh = wv >> 2, jq = wv & 3;
    const int j  = jq * 64 + lane;
    {
        const float* ajp = ajT + (b * HID + kh * 64) * NN + j;
        const int aoff = __builtin_amdgcn_readfirstlane((b * HID + kh * 64) * NN + i0);
        const float* aip = aiT + aoff;
        const float* w2p = w_a2 + kh * 64;

        float acc[8] = {0,0,0,0,0,0,0,0};
        float pa[16], pb[16];
        #pragma unroll
        for (int t = 0; t < 16; ++t) pa[t] = ajp[t * NN];
        #pragma unroll
        for (int t = 0; t < 16; ++t) pb[t] = ajp[(16 + t) * NN];

        #pragma unroll
        for (int c = 0; c < 64; c += 32) {
            #pragma unroll
            for (int t = 0; t < 16; ++t) {
                const int kk = c + t;
                const float8 s8 = *(const float8*)(aip + kk * NN);
                const float wk  = w2p[kk];
                const float a   = pa[t];
                #pragma unroll
                for (int r = 0; r < 8; ++r)
                    acc[r] += fmaxf(s8[r] + a, 0.f) * wk;
            }
            if (c + 32 < 64) {
                #pragma unroll
                for (int t = 0; t < 16; ++t) pa[t] = ajp[(c + 32 + t) * NN];
            }
            #pragma unroll
            for (int t = 0; t < 16; ++t) {
                const int kk = c + 16 + t;
                const float8 s8 = *(const float8*)(aip + kk * NN);
                const float wk  = w2p[kk];
                const float a   = pb[t];
                #pragma unroll
                for (int r = 0; r < 8; ++r)
                    acc[r] += fmaxf(s8[r] + a, 0.f) * wk;
            }
            if (c + 48 < 64) {
                #pragma unroll
                for (int t = 0; t < 16; ++t) pb[t] = ajp[(c + 48 + t) * NN];
            }
        }
        #pragma unroll
        for (int r = 0; r < 8; ++r)
            buf[(kh * 8 + r) * NN + j] = acc[r];
    }
    __syncthreads();

    // ---- mask + softmax: wave wv owns row wv ----
    {
        const float ba2 = b_a2[0];
        const float4 u = *(const float4*)&buf[(0 + wv) * NN + 4 * lane];
        const float4 v = *(const float4*)&buf[(8 + wv) * NN + 4 * lane];
        const float e0 = am.x ? u.x + v.x + ba2 : -1e9f;
        const float e1 = am.y ? u.y + v.y + ba2 : -1e9f;
        const float e2 = am.z ? u.z + v.z + ba2 : -1e9f;
        const float e3 = am.w ? u.w + v.w + ba2 : -1e9f;
        float m = fmaxf(fmaxf(e0, e1), fmaxf(e2, e3));
        #pragma unroll
        for (int off = 32; off; off >>= 1) m = fmaxf(m, __shfl_xor(m, off));
        const float p0 = __expf(e0 - m), p1 = __expf(e1 - m);
        const float p2 = __expf(e2 - m), p3 = __expf(e3 - m);
        float s = (p0 + p1) + (p2 + p3);
        #pragma unroll
        for (int off = 32; off; off >>= 1) s += __shfl_xor(s, off);
        const float inv = 1.f / s;
        const float4 pv = {p0 * inv, p1 * inv, p2 * inv, p3 * inv};
        *(float4*)&ep[wv * NN + 4 * lane] = pv;
    }
    __syncthreads();

    // ---- phase B: out = attn @ g, 4-way j-split ----
    const int k = tid & 127, qh = tid >> 7;   // j in [64qh, 64qh+64)
    {
        float o[8] = {0,0,0,0,0,0,0,0};
        const float* gb = g + (b * NN + qh * 64) * HID + k;
        const int jb = qh * 64;
        #pragma unroll 4
        for (int jq2 = 0; jq2 < 64; jq2 += 4) {
            const float g0 = gb[(jq2 + 0) * HID];
            const float g1 = gb[(jq2 + 1) * HID];
            const float g2 = gb[(jq2 + 2) * HID];
            const float g3 = gb[(jq2 + 3) * HID];
            #pragma unroll
            for (int r = 0; r < 8; ++r) {
                const float4 pv = *(const float4*)&ep[r * NN + jb + jq2];
                o[r] += pv.x * g0 + pv.y * g1 + pv.z * g2 + pv.w * g3;
            }
        }
        #pragma unroll
        for (int r = 0; r < 8; ++r) buf[(qh * 8 + r) * HID + k] = o[r];
    }
    __syncthreads();

    // ---- final reduce: thread (k,qh) -> rows 2qh, 2qh+1 ----
    {
        const float bo = b_out[k];
        #pragma unroll
        for (int r2 = 0; r2 < 2; ++r2) {
            const int r = 2 * qh + r2;
            out[(b * NN + i0 + r) * HID + k] =
                (buf[(0 + r) * HID + k]  + buf[(8 + r) * HID + k]) +
                (buf[(16 + r) * HID + k] + buf[(24 + r) * HID + k]) + bo;
        }
    }
}

extern "C" void kernel_launch(void* const* d_in, const int* in_sizes, int n_in,
                              void* d_out, int out_size, void* d_ws, size_t ws_size,
                              hipStream_t stream) {
    const float* x     = (const float*)d_in[0];
    const int*   adj   = (const int*)  d_in[1];
    const float* W_fc  = (const float*)d_in[2];
    const float* b_fc  = (const float*)d_in[3];
    const float* W_a1  = (const float*)d_in[4];
    const float* b_a1  = (const float*)d_in[5];
    const float* w_a2  = (const float*)d_in[6];
    const float* b_a2  = (const float*)d_in[7];
    const float* W_out = (const float*)d_in[8];
    const float* b_out = (const float*)d_in[9];
    float* out = (float*)d_out;

    float* ws  = (float*)d_ws;
    float* aiT = ws;                      // aiT[b][k][n]
    float* ajT = ws + BS * NN * HID;      // ajT[b][k][n]
    float* g   = ws + 2 * BS * NN * HID;  // g = h@W_out, [b][n][k]

    gat_k1<<<BS * NN / 8, 512, 0, stream>>>(x, W_fc, b_fc, W_a1, b_a1, W_out,
                                            aiT, ajT, g);
    gat_k2<<<BS * (NN / 8), 512, 0, stream>>>(aiT, ajT, g, adj, w_a2, b_a2,
                                              b_out, out);
}

// Round 11
// 42.409 us; speedup vs baseline: 1.0393x; 1.0393x over previous
//
#include <hip/hip_runtime.h>

#define BS  16
#define NN  256
#define HID 128

// 512 blocks: XCD x gets swz in [64x, 64x+64) = batches 2x, 2x+1.
__device__ __forceinline__ int xcd_swz(int bid) {
    return (bid & 7) * 64 + (bid >> 3);
}

// ---------------------------------------------------------------------------
// K1: 512 blocks, 512 threads, 8 rows/block. Split-K quarters; weights read
// once per block; LDS reduction. (R9 configuration, unchanged.)
// ---------------------------------------------------------------------------
__global__ __launch_bounds__(512, 4) void gat_k1(
    const float* __restrict__ x, const float* __restrict__ W_fc,
    const float* __restrict__ b_fc, const float* __restrict__ W_a1,
    const float* __restrict__ b_a1, const float* __restrict__ W_out,
    float* __restrict__ aiT, float* __restrict__ ajT, float* __restrict__ g)
{
    __shared__ __align__(16) float xs[8][HID];           // 4KB
    __shared__ __align__(16) float hs[8][HID];           // 4KB
    __shared__ __align__(16) float red[4][8][HID];       // 16KB

    const int tid = threadIdx.x;
    const int k   = tid & 127;
    const int q   = tid >> 7;                 // 0..3
    const int swz = xcd_swz(blockIdx.x);
    const int r0  = swz * 8;                  // flat row = b*NN + n0
    const int b   = r0 >> 8;
    const int n0  = r0 & 255;

    for (int t = tid; t < 8 * HID; t += 512)
        xs[t >> 7][t & 127] = x[r0 * HID + t];
    __syncthreads();

    // ---- phase 1: h partials, split-K quarter d in [32q, 32q+32) ----
    {
        float acc[8] = {0,0,0,0,0,0,0,0};
        const int dq = 32 * q;
        #pragma unroll 2
        for (int d = 0; d < 32; d += 4) {
            float w[4];
            #pragma unroll
            for (int t = 0; t < 4; ++t) w[t] = W_fc[(dq + d + t) * HID + k];
            #pragma unroll
            for (int r = 0; r < 8; ++r) {
                const float4 xv = *(const float4*)&xs[r][dq + d];
                acc[r] += xv.x * w[0] + xv.y * w[1] + xv.z * w[2] + xv.w * w[3];
            }
        }
        #pragma unroll
        for (int r = 0; r < 8; ++r) red[q][r][k] = acc[r];
    }
    __syncthreads();

    // ---- reduce h: thread (k,q) -> rows 2q, 2q+1 ----
    {
        const float bf = b_fc[k];
        #pragma unroll
        for (int r2 = 0; r2 < 2; ++r2) {
            const int r = 2 * q + r2;
            hs[r][k] = (red[0][r][k] + red[1][r][k])
                     + (red[2][r][k] + red[3][r][k]) + bf;
        }
    }
    __syncthreads();

    // ---- phase 2a: q0/q1 -> ai d-halves; q2/q3 -> aj d-halves ----
    {
        const int is_aj = q >> 1;
        const int half  = q & 1;
        const float* Wp = W_a1 + (is_aj * HID + half * 64) * HID;
        float acc[8] = {0,0,0,0,0,0,0,0};
        const int hb = half * 64;
        #pragma unroll 2
        for (int d = 0; d < 64; d += 4) {
            float w[4];
            #pragma unroll
            for (int t = 0; t < 4; ++t) w[t] = Wp[(d + t) * HID + k];
            #pragma unroll
            for (int r = 0; r < 8; ++r) {
                const float4 hv = *(const float4*)&hs[r][hb + d];
                acc[r] += hv.x * w[0] + hv.y * w[1] + hv.z * w[2] + hv.w * w[3];
            }
        }
        #pragma unroll
        for (int r = 0; r < 8; ++r) red[q][r][k] = acc[r];
    }
    __syncthreads();

    // ---- reduce + transposed store: q selects (ai|aj, row-quad) ----
    {
        const int is_aj = q >> 1;
        const int rb4   = (q & 1) * 4;
        const float bias = is_aj ? 0.f : b_a1[k];
        const int p0 = 2 * is_aj, p1 = 2 * is_aj + 1;
        float4 v;
        v.x = red[p0][rb4 + 0][k] + red[p1][rb4 + 0][k] + bias;
        v.y = red[p0][rb4 + 1][k] + red[p1][rb4 + 1][k] + bias;
        v.z = red[p0][rb4 + 2][k] + red[p1][rb4 + 2][k] + bias;
        v.w = red[p0][rb4 + 3][k] + red[p1][rb4 + 3][k] + bias;
        float* dst = (is_aj ? ajT : aiT) + (b * HID + k) * NN + n0 + rb4;
        *(float4*)dst = v;
    }
    __syncthreads();   // red free again

    // ---- phase 2b: g partials, split-K quarters ----
    {
        float acc[8] = {0,0,0,0,0,0,0,0};
        const int dq = 32 * q;
        #pragma unroll 2
        for (int d = 0; d < 32; d += 4) {
            float w[4];
            #pragma unroll
            for (int t = 0; t < 4; ++t) w[t] = W_out[(dq + d + t) * HID + k];
            #pragma unroll
            for (int r = 0; r < 8; ++r) {
                const float4 hv = *(const float4*)&hs[r][dq + d];
                acc[r] += hv.x * w[0] + hv.y * w[1] + hv.z * w[2] + hv.w * w[3];
            }
        }
        #pragma unroll
        for (int r = 0; r < 8; ++r) red[q][r][k] = acc[r];
    }
    __syncthreads();

    // ---- reduce g: thread (k,q) -> rows 2q, 2q+1 ----
    {
        #pragma unroll
        for (int r2 = 0; r2 < 2; ++r2) {
            const int r = 2 * q + r2;
            g[(r0 + r) * HID + k] = (red[0][r][k] + red[1][r][k])
                                  + (red[2][r][k] + red[3][r][k]);
        }
    }
}

// ---------------------------------------------------------------------------
// K2: 512 blocks, 512 threads, 8-row i-tile (R9 structure). Phase A uses the
// identity relu(ai+a)*w = (max(ai,-a) + a)*w with the row-independent
// sum(a*w) hoisted: 9 VALU per k per 4-row group instead of 12+.
// ---------------------------------------------------------------------------
__global__ __launch_bounds__(512, 4) void gat_k2(
    const float* __restrict__ aiT, const float* __restrict__ ajT,
    const float* __restrict__ g,  const int* __restrict__ adj,
    const float* __restrict__ w_a2, const float* __restrict__ b_a2,
    const float* __restrict__ b_out, float* __restrict__ out)
{
    __shared__ __align__(16) float aiw[HID][8];          // 4KB, [k][row]
    __shared__ __align__(16) float w2s[HID];
    __shared__ __align__(16) float ep[8][NN];            // 8KB
    __shared__ __align__(16) float red[4][8][HID];       // 16KB

    const int tid = threadIdx.x;
    const int swz = xcd_swz(blockIdx.x);
    const int b   = swz >> 5;
    const int i0  = (swz & 31) * 8;
    const int wv  = tid >> 6, lane = tid & 63;

    for (int t = tid; t < HID * 8; t += 512) {
        const int kk = t >> 3, r = t & 7;
        aiw[kk][r] = aiT[(b * HID + kk) * NN + i0 + r];
    }
    if (tid < HID) w2s[tid] = w_a2[tid];
    __syncthreads();

    // ---- phase A: e[8 rows][j], wave covers 32 j x all 8 rows ----
    const int jj = 32 * wv + (lane & 31);
    const int rg = lane >> 5;                 // rows 4rg .. 4rg+3
    {
        int am[4];
        #pragma unroll
        for (int r = 0; r < 4; ++r)
            am[r] = adj[(b * NN + i0 + 4 * rg + r) * NN + jj];

        const float* ajp = ajT + b * HID * NN + jj;
        float acc[4] = {0.f, 0.f, 0.f, 0.f};
        float saw = 0.f;                      // sum_k a*wk (row-independent)
        #pragma unroll 8
        for (int kk = 0; kk < HID; ++kk) {
            const float a   = ajp[kk * NN];
            const float4 f4 = *(const float4*)&aiw[kk][4 * rg];
            const float wk  = w2s[kk];
            saw = __builtin_fmaf(a, wk, saw);
            acc[0] = __builtin_fmaf(fmaxf(f4.x, -a), wk, acc[0]);
            acc[1] = __builtin_fmaf(fmaxf(f4.y, -a), wk, acc[1]);
            acc[2] = __builtin_fmaf(fmaxf(f4.z, -a), wk, acc[2]);
            acc[3] = __builtin_fmaf(fmaxf(f4.w, -a), wk, acc[3]);
        }
        const float base = saw + b_a2[0];
        #pragma unroll
        for (int r = 0; r < 4; ++r)
            ep[4 * rg + r][jj] = am[r] ? acc[r] + base : -1e9f;
    }
    __syncthreads();

    // ---- softmax: wave wv owns row wv ----
    {
        float4 e4 = *(const float4*)&ep[wv][4 * lane];
        float m = fmaxf(fmaxf(e4.x, e4.y), fmaxf(e4.z, e4.w));
        #pragma unroll
        for (int off = 32; off; off >>= 1) m = fmaxf(m, __shfl_xor(m, off));
        const float p0 = __expf(e4.x - m), p1 = __expf(e4.y - m);
        const float p2 = __expf(e4.z - m), p3 = __expf(e4.w - m);
        float s = (p0 + p1) + (p2 + p3);
        #pragma unroll
        for (int off = 32; off; off >>= 1) s += __shfl_xor(s, off);
        const float inv = 1.f / s;
        const float4 pv = {p0 * inv, p1 * inv, p2 * inv, p3 * inv};
        *(float4*)&ep[wv][4 * lane] = pv;
    }
    __syncthreads();

    // ---- phase B: out = attn @ g, j in quarters ----
    const int k = tid & 127, qh = tid >> 7;   // j in [64qh, 64qh+64)
    {
        float o[8] = {0,0,0,0,0,0,0,0};
        const float* gb = g + (b * NN + qh * 64) * HID + k;
        const int jb = qh * 64;
        #pragma unroll 2
        for (int jq = 0; jq < 64; jq += 4) {
            const float g0 = gb[(jq + 0) * HID];
            const float g1 = gb[(jq + 1) * HID];
            const float g2 = gb[(jq + 2) * HID];
            const float g3 = gb[(jq + 3) * HID];
            #pragma unroll
            for (int r = 0; r < 8; ++r) {
                const float4 pv = *(const float4*)&ep[r][jb + jq];
                o[r] += pv.x * g0 + pv.y * g1 + pv.z * g2 + pv.w * g3;
            }
        }
        #pragma unroll
        for (int r = 0; r < 8; ++r) red[qh][r][k] = o[r];
    }
    __syncthreads();

    // ---- final reduce: thread (k,qh) -> rows 2qh, 2qh+1 ----
    {
        const float bo = b_out[k];
        #pragma unroll
        for (int r2 = 0; r2 < 2; ++r2) {
            const int r = 2 * qh + r2;
            out[(b * NN + i0 + r) * HID + k] =
                (red[0][r][k] + red[1][r][k]) +
                (red[2][r][k] + red[3][r][k]) + bo;
        }
    }
}

extern "C" void kernel_launch(void* const* d_in, const int* in_sizes, int n_in,
                              void* d_out, int out_size, void* d_ws, size_t ws_size,
                              hipStream_t stream) {
    const float* x     = (const float*)d_in[0];
    const int*   adj   = (const int*)  d_in[1];
    const float* W_fc  = (const float*)d_in[2];
    const float* b_fc  = (const float*)d_in[3];
    const float* W_a1  = (const float*)d_in[4];
    const float* b_a1  = (const float*)d_in[5];
    const float* w_a2  = (const float*)d_in[6];
    const float* b_a2  = (const float*)d_in[7];
    const float* W_out = (const float*)d_in[8];
    const float* b_out = (const float*)d_in[9];
    float* out = (float*)d_out;

    float* ws  = (float*)d_ws;
    float* aiT = ws;                      // aiT[b][k][n]
    float* ajT = ws + BS * NN * HID;      // ajT[b][k][n]
    float* g   = ws + 2 * BS * NN * HID;  // g = h@W_out, [b][n][k]

    gat_k1<<<BS * NN / 8, 512, 0, stream>>>(x, W_fc, b_fc, W_a1, b_a1, W_out,
                                            aiT, ajT, g);
    gat_k2<<<BS * (NN / 8), 512, 0, stream>>>(aiT, ajT, g, adj, w_a2, b_a2,
                                              b_out, out);
}